// Round 5
// baseline (188.791 us; speedup 1.0000x reference)
//
#include <hip/hip_runtime.h>

typedef __attribute__((ext_vector_type(8))) short short8;
typedef __attribute__((ext_vector_type(4))) float floatx4;

static __device__ __forceinline__ unsigned short f2bf(float f) {
    unsigned u = __float_as_uint(f);
    u += 0x7FFFu + ((u >> 16) & 1u);
    return (unsigned short)(u >> 16);
}

// ================= single fused kernel =================
// R5: ONE 1024-thread block per CU (16 waves), tile = 256 samples,
// LDS = 96KB (W1 32K + W2 32K + sH 32K) -> 1 block/CU with 64KB slack,
// 16 waves/CU = 4 waves/SIMD GUARANTEED by a single resident block.
// R4's lesson: 2 x 80KB = exactly the 160KB pool -> runtime could NOT
// co-schedule 2 blocks (alloc padding/reserved LDS), occupancy stayed at
// 8 waves/CU (18%) and dur got worse (70us). Single-block residency
// sidesteps the pool-boundary problem entirely.
// __launch_bounds__(1024,1): empirically (R3/R4) arg2 acts as blocks/CU;
// 1 block = 16 waves/CU = 4 waves/SIMD -> 128-VGPR cap; natural usage is
// 116 -> zero spill (R3's spill disaster was the 64-reg cap).
//
// Lane mapping (R2): lane (q,l16) of wave w owns sample w*16+l16 with
// coord chunks {8q..8q+7} and {32+8q..+7}:
//  - quad reduction = shfl_xor 16/32,
//  - post-solve bf16 values ARE the MFMA A-frags a0/a1 (no xs round-trip),
//  - e^s fans out with 4 __shfl.
// Newton: log-Newton on G=ln F in base 2 (s += log2(v)*v/dv2), init =
// step from s=0; wave-uniform early break __all(|v-1|<1e-5) (fp32 noise
// floor ~3e-7..1e-6; |ds|~2.5e-6 -> out rel err ~1e-5 << bf16 noise).
// The -1 of F applies ONCE, post-reduction.
//
// LDS XOR swizzle (chunk c of row R at c^(R&7)) -> <=2-way bank aliasing,
// free on CDNA4. sH strip is wave-private (wave w only touches rows
// 16w..16w+15; same-wave LDS is in-order) -> ZERO __syncthreads in the
// tile loop.
__global__ __launch_bounds__(1024, 1) void fused_k(const float* __restrict__ x,
                                                   const float* __restrict__ r,
                                                   const float* __restrict__ W1f,
                                                   const float* __restrict__ b1,
                                                   const float* __restrict__ W2f,
                                                   const float* __restrict__ b2,
                                                   float* __restrict__ out,
                                                   int tiles_per_block) {
    __shared__ unsigned short sW1[256 * 64];  // 32 KB, row-major [h][k], swizzled
    __shared__ unsigned short sW2[64 * 256];  // 32 KB, row-major [o][h], swizzled
    __shared__ unsigned short sH[256 * 64];   // 32 KB, H-chunk strip, swizzled

    int tid = threadIdx.x;

    // ---- stage W1 [256x64] fp32 -> bf16 swizzled (2048 uint4 of 8 bf16)
    const float4* w1f4 = (const float4*)W1f;
#pragma unroll
    for (int c = 0; c < 2; ++c) {
        int g = tid + c * 1024;
        float4 lo = w1f4[2 * g], hi = w1f4[2 * g + 1];
        uint4 p;
        p.x = (unsigned)f2bf(lo.x) | ((unsigned)f2bf(lo.y) << 16);
        p.y = (unsigned)f2bf(lo.z) | ((unsigned)f2bf(lo.w) << 16);
        p.z = (unsigned)f2bf(hi.x) | ((unsigned)f2bf(hi.y) << 16);
        p.w = (unsigned)f2bf(hi.z) | ((unsigned)f2bf(hi.w) << 16);
        int row = g >> 3, ch = g & 7;
        *(uint4*)&sW1[row * 64 + (ch ^ (row & 7)) * 8] = p;
    }
    // ---- stage W2 [64x256] fp32 -> bf16 swizzled
    const float4* w2f4 = (const float4*)W2f;
#pragma unroll
    for (int c = 0; c < 2; ++c) {
        int g = tid + c * 1024;
        float4 lo = w2f4[2 * g], hi = w2f4[2 * g + 1];
        uint4 p;
        p.x = (unsigned)f2bf(lo.x) | ((unsigned)f2bf(lo.y) << 16);
        p.y = (unsigned)f2bf(lo.z) | ((unsigned)f2bf(lo.w) << 16);
        p.z = (unsigned)f2bf(hi.x) | ((unsigned)f2bf(hi.y) << 16);
        p.w = (unsigned)f2bf(hi.z) | ((unsigned)f2bf(hi.w) << 16);
        int row = g >> 5, ch = g & 31;
        *(uint4*)&sW2[row * 256 + (ch ^ (row & 7)) * 8] = p;
    }
    __syncthreads();

    int wave = tid >> 6, lane = tid & 63;  // wave 0..15
    int q = lane >> 4, l16 = lane & 15;
    int sx = l16 & 7;  // swizzle key for rows indexed by l16

    float bias1[16];
#pragma unroll
    for (int n = 0; n < 16; ++n) bias1[n] = b1[n * 16 + l16];
    float bias2[4];
#pragma unroll
    for (int n = 0; n < 4; ++n) bias2[n] = b2[n * 16 + l16];

    // ---- per-thread rate chunks: coords {8q..8q+7} and {32+8q..+7}
    const float L2E2 = 2.8853900817779268f;  // 2*log2(e)
    float rl2[16];
    {
        const float4* r4 = (const float4*)r;
        float4 ra = r4[2 * q], rb = r4[2 * q + 1];
        float4 rc = r4[8 + 2 * q], rd = r4[8 + 2 * q + 1];
        rl2[0] = ra.x * L2E2; rl2[1] = ra.y * L2E2; rl2[2] = ra.z * L2E2; rl2[3] = ra.w * L2E2;
        rl2[4] = rb.x * L2E2; rl2[5] = rb.y * L2E2; rl2[6] = rb.z * L2E2; rl2[7] = rb.w * L2E2;
        rl2[8] = rc.x * L2E2; rl2[9] = rc.y * L2E2; rl2[10] = rc.z * L2E2; rl2[11] = rc.w * L2E2;
        rl2[12] = rd.x * L2E2; rl2[13] = rd.y * L2E2; rl2[14] = rd.z * L2E2; rl2[15] = rd.w * L2E2;
    }

    for (int tt = 0; tt < tiles_per_block; ++tt) {
        size_t m0 = ((size_t)blockIdx.x * tiles_per_block + tt) * 256;
        int myrow = wave * 16 + l16;  // 0..255

        // ---- load this thread's x chunks (sample myrow, coords 8q.. / 32+8q..)
        const float4* x4 = (const float4*)(x + (m0 + myrow) * 64);
        float4 va = x4[2 * q], vb = x4[2 * q + 1];
        float4 vc = x4[8 + 2 * q], vd = x4[8 + 2 * q + 1];
        float xv[16];
        xv[0] = va.x; xv[1] = va.y; xv[2] = va.z; xv[3] = va.w;
        xv[4] = vb.x; xv[5] = vb.y; xv[6] = vb.z; xv[7] = vb.w;
        xv[8] = vc.x; xv[9] = vc.y; xv[10] = vc.z; xv[11] = vc.w;
        xv[12] = vd.x; xv[13] = vd.y; xv[14] = vd.z; xv[15] = vd.w;

        float x2[16], rx2[16];
        float sum0 = 0.f, sumr = 0.f;
        int nz = 0;
#pragma unroll
        for (int j = 0; j < 16; ++j) {
            x2[j] = xv[j] * xv[j];
            rx2[j] = rl2[j] * x2[j];
            sum0 += x2[j];
            sumr += rx2[j];
            nz |= (fabsf(xv[j]) > 1e-12f) ? 1 : 0;
        }
        // quad reduction: the 4 owners of a sample differ in lane bits 4,5
        sum0 += __shfl_xor(sum0, 16); sum0 += __shfl_xor(sum0, 32);
        sumr += __shfl_xor(sumr, 16); sumr += __shfl_xor(sumr, 32);
        nz   |= __shfl_xor(nz, 16);   nz   |= __shfl_xor(nz, 32);

        float s = 0.f;
        if (nz) {
            // init = log-Newton step from s=0: s = log2(sum0)*sum0/sumr2
            s = __log2f(sum0) * sum0 * __builtin_amdgcn_rcpf(sumr);
#pragma unroll 1
            for (int it = 0; it < 10; ++it) {
                float ns = -s;
                float v = 0.f, dv = 0.f;
#pragma unroll
                for (int j = 0; j < 16; ++j) {
                    float e = __builtin_amdgcn_exp2f(ns * rl2[j]);
                    v = fmaf(e, x2[j], v);
                    dv = fmaf(e, rx2[j], dv);
                }
                v += __shfl_xor(v, 16);   v += __shfl_xor(v, 32);
                dv += __shfl_xor(dv, 16); dv += __shfl_xor(dv, 32);
                if (__all(fabsf(v - 1.f) < 1e-5f)) break;
                // log-Newton in base 2: s += log2(v)*v/dv2
                s += __log2f(v) * v * __builtin_amdgcn_rcpf(dv);
            }
        }

        // ---- A-frags directly from the solve: xs = x * 2^{-s*rl2/2}
        float hs = -0.5f * s;
        short8 a0, a1;
#pragma unroll
        for (int j = 0; j < 8; ++j)
            a0[j] = (short)f2bf(xv[j] * __builtin_amdgcn_exp2f(hs * rl2[j]));
#pragma unroll
        for (int j = 0; j < 8; ++j)
            a1[j] = (short)f2bf(xv[8 + j] * __builtin_amdgcn_exp2f(hs * rl2[8 + j]));

        // e^s, fan out to the lanes that scale samples q*4+reg
        float es = __builtin_amdgcn_exp2f(s * 1.4426950408889634f);
        float sc[4];
#pragma unroll
        for (int reg = 0; reg < 4; ++reg) sc[reg] = __shfl(es, q * 4 + reg);

        floatx4 oacc[4];
#pragma unroll
        for (int n = 0; n < 4; ++n) oacc[n] = (floatx4){0.f, 0.f, 0.f, 0.f};

#pragma unroll
        for (int hc = 0; hc < 4; ++hc) {
            // ---- GEMM1: H[:, hc*64 .. +63] = relu(Xs @ W1^T + b1), 4 n-subtiles
#pragma unroll
            for (int n = 0; n < 4; ++n) {
                int hcol = hc * 4 + n;            // 16-col subtile index (0..15)
                int row = hcol * 16 + l16;        // W1 row = h index
                short8 wb0 = *(const short8*)&sW1[row * 64 + (q ^ sx) * 8];
                short8 wb1 = *(const short8*)&sW1[row * 64 + ((q + 4) ^ sx) * 8];
                floatx4 acc = {0.f, 0.f, 0.f, 0.f};
                acc = __builtin_amdgcn_mfma_f32_16x16x32_bf16(a0, wb0, acc, 0, 0, 0);
                acc = __builtin_amdgcn_mfma_f32_16x16x32_bf16(a1, wb1, acc, 0, 0, 0);
                float bias = bias1[hcol];
#pragma unroll
                for (int reg = 0; reg < 4; ++reg) {
                    // C/D: col = l16, row = q*4+reg
                    float h = acc[reg] + bias;
                    h = h > 0.f ? h : 0.f;
                    int rr = wave * 16 + q * 4 + reg;  // 0..255, wave-private
                    int E = n * 16 + l16;  // h-local col within the 64-chunk
                    sH[rr * 64 + (((E >> 3) ^ (rr & 7)) * 8) + (E & 7)] = f2bf(h);
                }
            }
            // ---- GEMM2 partial: oacc += H_chunk @ W2_chunk^T
            short8 ha0 = *(const short8*)&sH[myrow * 64 + (q ^ sx) * 8];
            short8 ha1 = *(const short8*)&sH[myrow * 64 + ((q + 4) ^ sx) * 8];
#pragma unroll
            for (int n = 0; n < 4; ++n) {
                int row = n * 16 + l16;  // W2 row = o index
                short8 wb0 = *(const short8*)&sW2[row * 256 + (hc * 8 + (q ^ sx)) * 8];
                short8 wb1 = *(const short8*)&sW2[row * 256 + (hc * 8 + ((q + 4) ^ sx)) * 8];
                oacc[n] = __builtin_amdgcn_mfma_f32_16x16x32_bf16(ha0, wb0, oacc[n], 0, 0, 0);
                oacc[n] = __builtin_amdgcn_mfma_f32_16x16x32_bf16(ha1, wb1, oacc[n], 0, 0, 0);
            }
        }
        // ---- epilogue: out = (H @ W2^T + b2) * e^s
#pragma unroll
        for (int n = 0; n < 4; ++n) {
#pragma unroll
            for (int reg = 0; reg < 4; ++reg) {
                float o = (oacc[n][reg] + bias2[n]) * sc[reg];
                out[(m0 + wave * 16 + q * 4 + reg) * 64 + n * 16 + l16] = o;
            }
        }
    }
}

extern "C" void kernel_launch(void* const* d_in, const int* in_sizes, int n_in,
                              void* d_out, int out_size, void* d_ws, size_t ws_size,
                              hipStream_t stream) {
    const float* x  = (const float*)d_in[0];
    const float* r  = (const float*)d_in[1];
    const float* W1 = (const float*)d_in[2];
    const float* b1 = (const float*)d_in[3];
    const float* W2 = (const float*)d_in[4];
    const float* b2 = (const float*)d_in[5];
    float* out = (float*)d_out;
    int B = in_sizes[0] / 64;  // 262144

    int tiles = B / 256;           // 1024 tiles of 256 samples
    int blocks = 256;              // exactly 1 per CU
    int tpb = tiles / blocks;      // 4

    fused_k<<<blocks, 1024, 0, stream>>>(x, r, W1, b1, W2, b2, out, tpb);
}

// Round 6
// 146.378 us; speedup vs baseline: 1.2898x; 1.2898x over previous
//
#include <hip/hip_runtime.h>

typedef __attribute__((ext_vector_type(8))) short short8;
typedef __attribute__((ext_vector_type(4))) float floatx4;

static __device__ __forceinline__ unsigned short f2bf(float f) {
    unsigned u = __float_as_uint(f);
    u += 0x7FFFu + ((u >> 16) & 1u);
    return (unsigned short)(u >> 16);
}

// ================= single fused kernel =================
// R6: 512-thread blocks (8 waves), tile = 128 samples, LDS = 72KB
// (W1 32K + W2 32K + sH 8K) -> 2 blocks/CU (144KB <= 160KB pool; R2
// PROVED 2x72KB co-resides, R4 proved 2x80KB does NOT) = 16 waves/CU =
// 4 waves/SIMD. __launch_bounds__(512,2) is the only bound empirically
// giving 116 VGPRs (R3 (512,4) -> 64-reg spill; R5 (1024,1) -> 64-reg
// spill; R4 (512,2) -> 116, clean).
// sH shrink: hc loop now 8 chunks of 32 h-cols (was 4x64). Per hc:
// GEMM1 does 2 n-subtiles (2x2 MFMA), GEMM2 one K=32 MFMA per n.
// Total MFMA/writes per tile unchanged; sH = [128][32] = 8KB, 4 chunks
// of 16B per row, XOR swizzle chunk^(row&3).
//
// Lane mapping (R2): lane (q,l16) of wave w owns sample w*16+l16 with
// coord chunks {8q..8q+7} and {32+8q..+7}:
//  - quad reduction = shfl_xor 16/32,
//  - post-solve bf16 values ARE the MFMA A-frags a0/a1 (no xs round-trip),
//  - e^s fans out with 4 __shfl.
// Newton: log-Newton on G=ln F in base 2 (s += log2(v)*v/dv2), init =
// step from s=0; wave-uniform early break __all(|v-1|<1e-5) (fp32 noise
// floor ~3e-7..1e-6; |ds|~2.5e-6 -> out rel err ~1e-5 << bf16 noise).
// The -1 of F applies ONCE, post-reduction.
//
// sH strip is wave-private (wave w only touches rows 16w..16w+15;
// same-wave LDS is in-order) -> ZERO __syncthreads in the tile loop.
__global__ __launch_bounds__(512, 2) void fused_k(const float* __restrict__ x,
                                                  const float* __restrict__ r,
                                                  const float* __restrict__ W1f,
                                                  const float* __restrict__ b1,
                                                  const float* __restrict__ W2f,
                                                  const float* __restrict__ b2,
                                                  float* __restrict__ out,
                                                  int tiles_per_block) {
    __shared__ unsigned short sW1[256 * 64];  // 32 KB, row-major [h][k], swizzled
    __shared__ unsigned short sW2[64 * 256];  // 32 KB, row-major [o][h], swizzled
    __shared__ unsigned short sH[128 * 32];   //  8 KB, 32-col H strip, swizzled

    int tid = threadIdx.x;

    // ---- stage W1 [256x64] fp32 -> bf16 swizzled (2048 uint4 of 8 bf16)
    const float4* w1f4 = (const float4*)W1f;
#pragma unroll
    for (int c = 0; c < 4; ++c) {
        int g = tid + c * 512;
        float4 lo = w1f4[2 * g], hi = w1f4[2 * g + 1];
        uint4 p;
        p.x = (unsigned)f2bf(lo.x) | ((unsigned)f2bf(lo.y) << 16);
        p.y = (unsigned)f2bf(lo.z) | ((unsigned)f2bf(lo.w) << 16);
        p.z = (unsigned)f2bf(hi.x) | ((unsigned)f2bf(hi.y) << 16);
        p.w = (unsigned)f2bf(hi.z) | ((unsigned)f2bf(hi.w) << 16);
        int row = g >> 3, ch = g & 7;
        *(uint4*)&sW1[row * 64 + (ch ^ (row & 7)) * 8] = p;
    }
    // ---- stage W2 [64x256] fp32 -> bf16 swizzled
    const float4* w2f4 = (const float4*)W2f;
#pragma unroll
    for (int c = 0; c < 4; ++c) {
        int g = tid + c * 512;
        float4 lo = w2f4[2 * g], hi = w2f4[2 * g + 1];
        uint4 p;
        p.x = (unsigned)f2bf(lo.x) | ((unsigned)f2bf(lo.y) << 16);
        p.y = (unsigned)f2bf(lo.z) | ((unsigned)f2bf(lo.w) << 16);
        p.z = (unsigned)f2bf(hi.x) | ((unsigned)f2bf(hi.y) << 16);
        p.w = (unsigned)f2bf(hi.z) | ((unsigned)f2bf(hi.w) << 16);
        int row = g >> 5, ch = g & 31;
        *(uint4*)&sW2[row * 256 + (ch ^ (row & 7)) * 8] = p;
    }
    __syncthreads();

    int wave = tid >> 6, lane = tid & 63;
    int q = lane >> 4, l16 = lane & 15;
    int sx = l16 & 7;  // swizzle key for rows indexed by l16

    float bias1[16];
#pragma unroll
    for (int n = 0; n < 16; ++n) bias1[n] = b1[n * 16 + l16];
    float bias2[4];
#pragma unroll
    for (int n = 0; n < 4; ++n) bias2[n] = b2[n * 16 + l16];

    // ---- per-thread rate chunks: coords {8q..8q+7} and {32+8q..+7}
    const float L2E2 = 2.8853900817779268f;  // 2*log2(e)
    float rl2[16];
    {
        const float4* r4 = (const float4*)r;
        float4 ra = r4[2 * q], rb = r4[2 * q + 1];
        float4 rc = r4[8 + 2 * q], rd = r4[8 + 2 * q + 1];
        rl2[0] = ra.x * L2E2; rl2[1] = ra.y * L2E2; rl2[2] = ra.z * L2E2; rl2[3] = ra.w * L2E2;
        rl2[4] = rb.x * L2E2; rl2[5] = rb.y * L2E2; rl2[6] = rb.z * L2E2; rl2[7] = rb.w * L2E2;
        rl2[8] = rc.x * L2E2; rl2[9] = rc.y * L2E2; rl2[10] = rc.z * L2E2; rl2[11] = rc.w * L2E2;
        rl2[12] = rd.x * L2E2; rl2[13] = rd.y * L2E2; rl2[14] = rd.z * L2E2; rl2[15] = rd.w * L2E2;
    }

    for (int tt = 0; tt < tiles_per_block; ++tt) {
        size_t m0 = ((size_t)blockIdx.x * tiles_per_block + tt) * 128;
        int myrow = wave * 16 + l16;  // 0..127
        int rsw = myrow & 3;          // sH read swizzle key

        // ---- load this thread's x chunks (sample myrow, coords 8q.. / 32+8q..)
        const float4* x4 = (const float4*)(x + (m0 + myrow) * 64);
        float4 va = x4[2 * q], vb = x4[2 * q + 1];
        float4 vc = x4[8 + 2 * q], vd = x4[8 + 2 * q + 1];
        float xv[16];
        xv[0] = va.x; xv[1] = va.y; xv[2] = va.z; xv[3] = va.w;
        xv[4] = vb.x; xv[5] = vb.y; xv[6] = vb.z; xv[7] = vb.w;
        xv[8] = vc.x; xv[9] = vc.y; xv[10] = vc.z; xv[11] = vc.w;
        xv[12] = vd.x; xv[13] = vd.y; xv[14] = vd.z; xv[15] = vd.w;

        float x2[16], rx2[16];
        float sum0 = 0.f, sumr = 0.f;
        int nz = 0;
#pragma unroll
        for (int j = 0; j < 16; ++j) {
            x2[j] = xv[j] * xv[j];
            rx2[j] = rl2[j] * x2[j];
            sum0 += x2[j];
            sumr += rx2[j];
            nz |= (fabsf(xv[j]) > 1e-12f) ? 1 : 0;
        }
        // quad reduction: the 4 owners of a sample differ in lane bits 4,5
        sum0 += __shfl_xor(sum0, 16); sum0 += __shfl_xor(sum0, 32);
        sumr += __shfl_xor(sumr, 16); sumr += __shfl_xor(sumr, 32);
        nz   |= __shfl_xor(nz, 16);   nz   |= __shfl_xor(nz, 32);

        float s = 0.f;
        if (nz) {
            // init = log-Newton step from s=0: s = log2(sum0)*sum0/sumr2
            s = __log2f(sum0) * sum0 * __builtin_amdgcn_rcpf(sumr);
#pragma unroll 1
            for (int it = 0; it < 10; ++it) {
                float ns = -s;
                float v = 0.f, dv = 0.f;
#pragma unroll
                for (int j = 0; j < 16; ++j) {
                    float e = __builtin_amdgcn_exp2f(ns * rl2[j]);
                    v = fmaf(e, x2[j], v);
                    dv = fmaf(e, rx2[j], dv);
                }
                v += __shfl_xor(v, 16);   v += __shfl_xor(v, 32);
                dv += __shfl_xor(dv, 16); dv += __shfl_xor(dv, 32);
                if (__all(fabsf(v - 1.f) < 1e-5f)) break;
                // log-Newton in base 2: s += log2(v)*v/dv2
                s += __log2f(v) * v * __builtin_amdgcn_rcpf(dv);
            }
        }

        // ---- A-frags directly from the solve: xs = x * 2^{-s*rl2/2}
        float hs = -0.5f * s;
        short8 a0, a1;
#pragma unroll
        for (int j = 0; j < 8; ++j)
            a0[j] = (short)f2bf(xv[j] * __builtin_amdgcn_exp2f(hs * rl2[j]));
#pragma unroll
        for (int j = 0; j < 8; ++j)
            a1[j] = (short)f2bf(xv[8 + j] * __builtin_amdgcn_exp2f(hs * rl2[8 + j]));

        // e^s, fan out to the lanes that scale samples q*4+reg
        float es = __builtin_amdgcn_exp2f(s * 1.4426950408889634f);
        float sc[4];
#pragma unroll
        for (int reg = 0; reg < 4; ++reg) sc[reg] = __shfl(es, q * 4 + reg);

        floatx4 oacc[4];
#pragma unroll
        for (int n = 0; n < 4; ++n) oacc[n] = (floatx4){0.f, 0.f, 0.f, 0.f};

#pragma unroll
        for (int hc = 0; hc < 8; ++hc) {
            // ---- GEMM1: H[:, hc*32 .. +31] = relu(Xs @ W1^T + b1), 2 n-subtiles
#pragma unroll
            for (int n = 0; n < 2; ++n) {
                int hcol = hc * 2 + n;            // 16-col subtile index (0..15)
                int row = hcol * 16 + l16;        // W1 row = h index
                short8 wb0 = *(const short8*)&sW1[row * 64 + (q ^ sx) * 8];
                short8 wb1 = *(const short8*)&sW1[row * 64 + ((q + 4) ^ sx) * 8];
                floatx4 acc = {0.f, 0.f, 0.f, 0.f};
                acc = __builtin_amdgcn_mfma_f32_16x16x32_bf16(a0, wb0, acc, 0, 0, 0);
                acc = __builtin_amdgcn_mfma_f32_16x16x32_bf16(a1, wb1, acc, 0, 0, 0);
                float bias = bias1[hcol];
#pragma unroll
                for (int reg = 0; reg < 4; ++reg) {
                    // C/D: col = l16, row = q*4+reg
                    float h = acc[reg] + bias;
                    h = h > 0.f ? h : 0.f;
                    int rr = wave * 16 + q * 4 + reg;  // 0..127, wave-private
                    int E = n * 16 + l16;  // h-local col within the 32-chunk
                    sH[rr * 32 + (((E >> 3) ^ (rr & 3)) * 8) + (E & 7)] = f2bf(h);
                }
            }
            // ---- GEMM2 partial (K=32): oacc += H_chunk @ W2_chunk^T
            short8 ha = *(const short8*)&sH[myrow * 32 + ((q ^ rsw) * 8)];
#pragma unroll
            for (int n = 0; n < 4; ++n) {
                int row = n * 16 + l16;  // W2 row = o index
                short8 wb = *(const short8*)&sW2[row * 256 + ((hc * 4 + q) ^ sx) * 8];
                oacc[n] = __builtin_amdgcn_mfma_f32_16x16x32_bf16(ha, wb, oacc[n], 0, 0, 0);
            }
        }
        // ---- epilogue: out = (H @ W2^T + b2) * e^s
#pragma unroll
        for (int n = 0; n < 4; ++n) {
#pragma unroll
            for (int reg = 0; reg < 4; ++reg) {
                float o = (oacc[n][reg] + bias2[n]) * sc[reg];
                out[(m0 + wave * 16 + q * 4 + reg) * 64 + n * 16 + l16] = o;
            }
        }
    }
}

extern "C" void kernel_launch(void* const* d_in, const int* in_sizes, int n_in,
                              void* d_out, int out_size, void* d_ws, size_t ws_size,
                              hipStream_t stream) {
    const float* x  = (const float*)d_in[0];
    const float* r  = (const float*)d_in[1];
    const float* W1 = (const float*)d_in[2];
    const float* b1 = (const float*)d_in[3];
    const float* W2 = (const float*)d_in[4];
    const float* b2 = (const float*)d_in[5];
    float* out = (float*)d_out;
    int B = in_sizes[0] / 64;  // 262144

    int tiles = B / 128;           // 2048 tiles of 128 samples
    int blocks = 512;              // 2 per CU
    int tpb = tiles / blocks;      // 4

    fused_k<<<blocks, 512, 0, stream>>>(x, r, W1, b1, W2, b2, out, tpb);
}

// Round 7
// 138.970 us; speedup vs baseline: 1.3585x; 1.0533x over previous
//
#include <hip/hip_runtime.h>

typedef __attribute__((ext_vector_type(8))) short short8;
typedef __attribute__((ext_vector_type(4))) float floatx4;

static __device__ __forceinline__ unsigned short f2bf(float f) {
    unsigned u = __float_as_uint(f);
    u += 0x7FFFu + ((u >> 16) & 1u);
    return (unsigned short)(u >> 16);
}

// ================= single fused kernel =================
// R7: ZERO-LDS H path. R6's per-hc sH round-trip (MFMA->relu->f2bf->
// ds_write->ds_read->MFMA, ~250-300cy un-hideable latency x8 hc + 4.3M
// bank conflicts) is removed entirely:
//  - GEMM1 swaps MFMA operands: mfma(wb, a) -> D[m=h_local=q*4+reg]
//    [n=sample=l16]: each lane accumulates H values FOR ITS OWN SAMPLE.
//  - h-dimension is globally PERMUTED at staging: slot(h) =
//    (2*(h>>5)+((h>>2)&1))*16 + ((h>>3)&3)*4 + (h&3), applied to W1 rows
//    and b1 (h is internal, so permuting W1-rows/b1 consistently while
//    reading W2 in logical-h order is exact). With this pi, the packed
//    outputs of subtile pair (2hc,2hc+1) concatenate to EXACTLY the
//    K=32 GEMM2 A-fragment (k=q*8+j): zero cross-lane, zero LDS writes.
//  - pack via v_cvt_pk_bf16_f32 (RNE, = f2bf); b1 folded into MFMA C-init
//    (one broadcast float4 read from 1KB sB1); b2 folded into oacc init.
// LDS = 32K(sW1) + 32K(sW2) + 1K(sB1) = 65KB -> 2 blocks/CU with margin.
// __launch_bounds__(512,2): the only bound empirically giving full regs
// (R3 (512,4)->64-cap spill, R5 (1024,1)->64-cap spill, R4/R6 (512,2) ok).
//
// Lane mapping (R2): lane (q,l16) of wave w owns sample w*16+l16 with
// coord chunks {8q..8q+7} and {32+8q..+7}; quad reduction = shfl_xor
// 16/32; post-solve bf16 values ARE the GEMM1 B-frags a0/a1; e^s fans
// out with 4 __shfl. Newton: log-Newton on G=ln F in base 2
// (s += log2(v)*v/dv2), init = step from s=0; wave-uniform early break
// __all(|v-1|<1e-5). The -1 of F applies ONCE, post-reduction.
// No LDS writes after staging -> ZERO __syncthreads in the tile loop.
__global__ __launch_bounds__(512, 2) void fused_k(const float* __restrict__ x,
                                                  const float* __restrict__ r,
                                                  const float* __restrict__ W1f,
                                                  const float* __restrict__ b1,
                                                  const float* __restrict__ W2f,
                                                  const float* __restrict__ b2,
                                                  float* __restrict__ out,
                                                  int tiles_per_block) {
    __shared__ unsigned short sW1[256 * 64];  // 32 KB, PERMUTED rows, swizzled
    __shared__ unsigned short sW2[64 * 256];  // 32 KB, logical-h order, swizzled
    __shared__ float sB1[256];                //  1 KB, b1 at permuted slots

    int tid = threadIdx.x;

    // ---- stage W1 [256x64] fp32 -> bf16, row-PERMUTED by pi, swizzled
    const float4* w1f4 = (const float4*)W1f;
#pragma unroll
    for (int c = 0; c < 4; ++c) {
        int g = tid + c * 512;
        int h = g >> 3, ch = g & 7;  // logical row, 8-elem chunk
        int prow = ((h >> 5) * 2 + ((h >> 2) & 1)) * 16 + ((h >> 3) & 3) * 4 + (h & 3);
        float4 lo = w1f4[2 * g], hi = w1f4[2 * g + 1];
        uint4 p;
        p.x = (unsigned)f2bf(lo.x) | ((unsigned)f2bf(lo.y) << 16);
        p.y = (unsigned)f2bf(lo.z) | ((unsigned)f2bf(lo.w) << 16);
        p.z = (unsigned)f2bf(hi.x) | ((unsigned)f2bf(hi.y) << 16);
        p.w = (unsigned)f2bf(hi.z) | ((unsigned)f2bf(hi.w) << 16);
        *(uint4*)&sW1[prow * 64 + (ch ^ (prow & 7)) * 8] = p;
    }
    // ---- stage W2 [64x256] fp32 -> bf16 swizzled (logical h order)
    const float4* w2f4 = (const float4*)W2f;
#pragma unroll
    for (int c = 0; c < 4; ++c) {
        int g = tid + c * 512;
        float4 lo = w2f4[2 * g], hi = w2f4[2 * g + 1];
        uint4 p;
        p.x = (unsigned)f2bf(lo.x) | ((unsigned)f2bf(lo.y) << 16);
        p.y = (unsigned)f2bf(lo.z) | ((unsigned)f2bf(lo.w) << 16);
        p.z = (unsigned)f2bf(hi.x) | ((unsigned)f2bf(hi.y) << 16);
        p.w = (unsigned)f2bf(hi.z) | ((unsigned)f2bf(hi.w) << 16);
        int row = g >> 5, ch = g & 31;
        *(uint4*)&sW2[row * 256 + (ch ^ (row & 7)) * 8] = p;
    }
    // ---- stage b1 at permuted slots
    if (tid < 256) {
        int h = tid;
        int prow = ((h >> 5) * 2 + ((h >> 2) & 1)) * 16 + ((h >> 3) & 3) * 4 + (h & 3);
        sB1[prow] = b1[h];
    }
    __syncthreads();

    int wave = tid >> 6, lane = tid & 63;
    int q = lane >> 4, l16 = lane & 15;
    int sx = l16 & 7;  // swizzle key for rows indexed by l16

    float bias2[4];
#pragma unroll
    for (int n = 0; n < 4; ++n) bias2[n] = b2[n * 16 + l16];

    // ---- per-thread rate chunks: coords {8q..8q+7} and {32+8q..+7}
    const float L2E2 = 2.8853900817779268f;  // 2*log2(e)
    float rl2[16];
    {
        const float4* r4 = (const float4*)r;
        float4 ra = r4[2 * q], rb = r4[2 * q + 1];
        float4 rc = r4[8 + 2 * q], rd = r4[8 + 2 * q + 1];
        rl2[0] = ra.x * L2E2; rl2[1] = ra.y * L2E2; rl2[2] = ra.z * L2E2; rl2[3] = ra.w * L2E2;
        rl2[4] = rb.x * L2E2; rl2[5] = rb.y * L2E2; rl2[6] = rb.z * L2E2; rl2[7] = rb.w * L2E2;
        rl2[8] = rc.x * L2E2; rl2[9] = rc.y * L2E2; rl2[10] = rc.z * L2E2; rl2[11] = rc.w * L2E2;
        rl2[12] = rd.x * L2E2; rl2[13] = rd.y * L2E2; rl2[14] = rd.z * L2E2; rl2[15] = rd.w * L2E2;
    }

    for (int tt = 0; tt < tiles_per_block; ++tt) {
        size_t m0 = ((size_t)blockIdx.x * tiles_per_block + tt) * 128;
        int myrow = wave * 16 + l16;  // 0..127

        // ---- load this thread's x chunks (sample myrow, coords 8q.. / 32+8q..)
        const float4* x4 = (const float4*)(x + (m0 + myrow) * 64);
        float4 va = x4[2 * q], vb = x4[2 * q + 1];
        float4 vc = x4[8 + 2 * q], vd = x4[8 + 2 * q + 1];
        float xv[16];
        xv[0] = va.x; xv[1] = va.y; xv[2] = va.z; xv[3] = va.w;
        xv[4] = vb.x; xv[5] = vb.y; xv[6] = vb.z; xv[7] = vb.w;
        xv[8] = vc.x; xv[9] = vc.y; xv[10] = vc.z; xv[11] = vc.w;
        xv[12] = vd.x; xv[13] = vd.y; xv[14] = vd.z; xv[15] = vd.w;

        float x2[16], rx2[16];
        float sum0 = 0.f, sumr = 0.f;
        int nz = 0;
#pragma unroll
        for (int j = 0; j < 16; ++j) {
            x2[j] = xv[j] * xv[j];
            rx2[j] = rl2[j] * x2[j];
            sum0 += x2[j];
            sumr += rx2[j];
            nz |= (fabsf(xv[j]) > 1e-12f) ? 1 : 0;
        }
        // quad reduction: the 4 owners of a sample differ in lane bits 4,5
        sum0 += __shfl_xor(sum0, 16); sum0 += __shfl_xor(sum0, 32);
        sumr += __shfl_xor(sumr, 16); sumr += __shfl_xor(sumr, 32);
        nz   |= __shfl_xor(nz, 16);   nz   |= __shfl_xor(nz, 32);

        float s = 0.f;
        if (nz) {
            // init = log-Newton step from s=0
            s = __log2f(sum0) * sum0 * __builtin_amdgcn_rcpf(sumr);
#pragma unroll 1
            for (int it = 0; it < 10; ++it) {
                float ns = -s;
                float v = 0.f, dv = 0.f;
#pragma unroll
                for (int j = 0; j < 16; ++j) {
                    float e = __builtin_amdgcn_exp2f(ns * rl2[j]);
                    v = fmaf(e, x2[j], v);
                    dv = fmaf(e, rx2[j], dv);
                }
                v += __shfl_xor(v, 16);   v += __shfl_xor(v, 32);
                dv += __shfl_xor(dv, 16); dv += __shfl_xor(dv, 32);
                if (__all(fabsf(v - 1.f) < 1e-5f)) break;
                // log-Newton in base 2: s += log2(v)*v/dv2
                s += __log2f(v) * v * __builtin_amdgcn_rcpf(dv);
            }
        }

        // ---- B-frags (GEMM1) directly from the solve: xs = x * 2^{-s*rl2/2}
        float hs = -0.5f * s;
        short8 a0, a1;
#pragma unroll
        for (int j = 0; j < 8; ++j)
            a0[j] = (short)f2bf(xv[j] * __builtin_amdgcn_exp2f(hs * rl2[j]));
#pragma unroll
        for (int j = 0; j < 8; ++j)
            a1[j] = (short)f2bf(xv[8 + j] * __builtin_amdgcn_exp2f(hs * rl2[8 + j]));

        // e^s, fan out to the lanes that scale samples q*4+reg
        float es = __builtin_amdgcn_exp2f(s * 1.4426950408889634f);
        float sc[4];
#pragma unroll
        for (int reg = 0; reg < 4; ++reg) sc[reg] = __shfl(es, q * 4 + reg);

        floatx4 oacc[4];
#pragma unroll
        for (int n = 0; n < 4; ++n)
            oacc[n] = (floatx4){bias2[n], bias2[n], bias2[n], bias2[n]};

#pragma unroll
        for (int hc = 0; hc < 8; ++hc) {
            // ---- GEMM1 (swapped), subtile pair (2hc, 2hc+1):
            // acc[reg] = H[logical h = hc*32 + q*8 + p*4 + reg][sample l16]
            unsigned pk0, pk1, pk2, pk3;
            {
                int t = hc * 2;
                int row = t * 16 + l16;
                short8 wb0 = *(const short8*)&sW1[row * 64 + (q ^ sx) * 8];
                short8 wb1 = *(const short8*)&sW1[row * 64 + ((q + 4) ^ sx) * 8];
                const float4 bb = *(const float4*)&sB1[t * 16 + q * 4];
                floatx4 acc = (floatx4){bb.x, bb.y, bb.z, bb.w};
                acc = __builtin_amdgcn_mfma_f32_16x16x32_bf16(wb0, a0, acc, 0, 0, 0);
                acc = __builtin_amdgcn_mfma_f32_16x16x32_bf16(wb1, a1, acc, 0, 0, 0);
                float h0 = fmaxf(acc[0], 0.f), h1 = fmaxf(acc[1], 0.f);
                float h2 = fmaxf(acc[2], 0.f), h3 = fmaxf(acc[3], 0.f);
                asm("v_cvt_pk_bf16_f32 %0, %1, %2" : "=v"(pk0) : "v"(h0), "v"(h1));
                asm("v_cvt_pk_bf16_f32 %0, %1, %2" : "=v"(pk1) : "v"(h2), "v"(h3));
            }
            {
                int t = hc * 2 + 1;
                int row = t * 16 + l16;
                short8 wb0 = *(const short8*)&sW1[row * 64 + (q ^ sx) * 8];
                short8 wb1 = *(const short8*)&sW1[row * 64 + ((q + 4) ^ sx) * 8];
                const float4 bb = *(const float4*)&sB1[t * 16 + q * 4];
                floatx4 acc = (floatx4){bb.x, bb.y, bb.z, bb.w};
                acc = __builtin_amdgcn_mfma_f32_16x16x32_bf16(wb0, a0, acc, 0, 0, 0);
                acc = __builtin_amdgcn_mfma_f32_16x16x32_bf16(wb1, a1, acc, 0, 0, 0);
                float h0 = fmaxf(acc[0], 0.f), h1 = fmaxf(acc[1], 0.f);
                float h2 = fmaxf(acc[2], 0.f), h3 = fmaxf(acc[3], 0.f);
                asm("v_cvt_pk_bf16_f32 %0, %1, %2" : "=v"(pk2) : "v"(h0), "v"(h1));
                asm("v_cvt_pk_bf16_f32 %0, %1, %2" : "=v"(pk3) : "v"(h2), "v"(h3));
            }
            // ---- A-frag for GEMM2 K-chunk hc: ha[j] = H[sample l16][hc*32+q*8+j]
            int4 hw = make_int4((int)pk0, (int)pk1, (int)pk2, (int)pk3);
            short8 ha = *(short8*)&hw;
#pragma unroll
            for (int n = 0; n < 4; ++n) {
                int orow = n * 16 + l16;  // W2 row = o index
                short8 wb = *(const short8*)&sW2[orow * 256 + ((hc * 4 + q) ^ sx) * 8];
                oacc[n] = __builtin_amdgcn_mfma_f32_16x16x32_bf16(ha, wb, oacc[n], 0, 0, 0);
            }
        }
        // ---- epilogue: out = (H @ W2^T + b2) * e^s   (b2 folded into init)
#pragma unroll
        for (int n = 0; n < 4; ++n) {
#pragma unroll
            for (int reg = 0; reg < 4; ++reg) {
                out[(m0 + wave * 16 + q * 4 + reg) * 64 + n * 16 + l16] =
                    oacc[n][reg] * sc[reg];
            }
        }
    }
}

extern "C" void kernel_launch(void* const* d_in, const int* in_sizes, int n_in,
                              void* d_out, int out_size, void* d_ws, size_t ws_size,
                              hipStream_t stream) {
    const float* x  = (const float*)d_in[0];
    const float* r  = (const float*)d_in[1];
    const float* W1 = (const float*)d_in[2];
    const float* b1 = (const float*)d_in[3];
    const float* W2 = (const float*)d_in[4];
    const float* b2 = (const float*)d_in[5];
    float* out = (float*)d_out;
    int B = in_sizes[0] / 64;  // 262144

    int tiles = B / 128;           // 2048 tiles of 128 samples
    int blocks = 512;              // 2 per CU
    int tpb = tiles / blocks;      // 4

    fused_k<<<blocks, 512, 0, stream>>>(x, r, W1, b1, W2, b2, out, tpb);
}